// Round 7
// baseline (102.781 us; speedup 1.0000x reference)
//
#include <hip/hip_runtime.h>
#include <hip/hip_bf16.h>

#define NH 4
#define HD 64
#define HID 256
#define SS 4096
#define KP 96

#define QFRAG_PER_HEAD (128 * 6 * 64 * 8)   // 393216 elems
#define KFRAG_PER_HEAD (64 * 12 * 64 * 8)   // 393216 elems
#define VFRAG_PER_HEAD (64 * 8 * 64 * 8)    // 262144 elems

typedef float f4 __attribute__((ext_vector_type(4)));
typedef float f16v __attribute__((ext_vector_type(16)));
typedef short bf8 __attribute__((ext_vector_type(8)));   // 8 bf16
typedef unsigned int u4v __attribute__((ext_vector_type(4)));

static __device__ __forceinline__ float fast_exp2(float x) {
#if __has_builtin(__builtin_amdgcn_exp2f)
    return __builtin_amdgcn_exp2f(x);
#else
    float r; asm("v_exp_f32 %0, %1" : "=v"(r) : "v"(x)); return r;
#endif
}

static __device__ __forceinline__ unsigned pack2(float a, float b) {
    unsigned ua = (unsigned)__bfloat16_as_ushort(__float2bfloat16(a));
    unsigned ub = (unsigned)__bfloat16_as_ushort(__float2bfloat16(b));
    return ua | (ub << 16);
}

// ---------------------------------------------------------------------------
// Setup: codon->group-id map + beta*log2e.
// ---------------------------------------------------------------------------
__global__ void setup_kernel(const float* __restrict__ syn,
                             int* __restrict__ gid, float* __restrict__ betaP)
{
    const int lane = threadIdx.x;          // 0..63
    int rep = 64;
    for (int j = 63; j >= 0; --j)
        if (syn[lane * 64 + j] != 0.0f) rep = j;
    if (rep == 64) rep = lane;
    unsigned long long m = __ballot(rep == lane);
    int id = (int)__popcll(m & ((2ull << rep) - 1ull)) - 1;
    if (id < 0) id = 0;
    gid[lane] = id;                                 // 0..20
    if (lane == 0) *betaP = syn[0] * 1.44269504088896f;
}

// ---------------------------------------------------------------------------
// Pack wq/wk/wv/wo into MFMA fragment-major bf16.
// ---------------------------------------------------------------------------
__global__ __launch_bounds__(256)
void pack_w_kernel(const float* __restrict__ wq, const float* __restrict__ wk,
                   const float* __restrict__ wv, const float* __restrict__ wo,
                   __hip_bfloat16* __restrict__ wpk)
{
    const int t = blockIdx.x * 256 + threadIdx.x;   // 0..32767
    const int mat = t >> 13;
    const int r = t & 8191;
    const int dt = r >> 10, ks = (r >> 6) & 15, lane = r & 63;
    const float* w = (mat == 0) ? wq : (mat == 1) ? wk : (mat == 2) ? wv : wo;
    const int row = dt * 32 + (lane & 31);
    const int col = ks * 16 + (lane >> 5) * 8;
    const f4 a = *(const f4*)&w[(size_t)row * 256 + col];
    const f4 b = *(const f4*)&w[(size_t)row * 256 + col + 4];
    union { unsigned u[4]; bf8 v; } o;
    o.u[0] = pack2(a[0], a[1]); o.u[1] = pack2(a[2], a[3]);
    o.u[2] = pack2(b[0], b[1]); o.u[3] = pack2(b[2], b[3]);
    *(bf8*)&wpk[(size_t)t * 8] = o.v;
}

// ---------------------------------------------------------------------------
// QKV projection via MFMA (unchanged from R6).
// ---------------------------------------------------------------------------
__global__ __launch_bounds__(256)
void qkv_mfma_kernel(const float* __restrict__ x,
                     const __hip_bfloat16* __restrict__ wpk,
                     const float* __restrict__ bq, const float* __restrict__ bk,
                     const float* __restrict__ bv,
                     const int* __restrict__ codons,
                     const int* __restrict__ gid, const float* __restrict__ betaP,
                     __hip_bfloat16* __restrict__ qfrag,
                     __hip_bfloat16* __restrict__ kfrag,
                     __hip_bfloat16* __restrict__ vfrag)
{
    const int bid = blockIdx.x;
    const int stile = bid / 6;            // 0..255
    const int grp = bid % 6;
    const int tid = threadIdx.x;
    const int w = tid >> 6, lane = tid & 63, hi = lane >> 5, l5 = lane & 31;

    const int bidx = stile >> 7;
    const int stl = stile & 127;
    const int hs = stl & 1, tkv = stl >> 1;

    __shared__ __hip_bfloat16 xs[32][256];

    {
        const int r0 = tid >> 5, c = tid & 31;
        #pragma unroll
        for (int it = 0; it < 4; ++it) {
            const int row = r0 + it * 8;
            const f4 a = *(const f4*)&x[(size_t)(stile * 32 + row) * HID + c * 8];
            const f4 b2 = *(const f4*)&x[(size_t)(stile * 32 + row) * HID + c * 8 + 4];
            union { unsigned u[4]; bf8 v; } o;
            o.u[0] = pack2(a[0], a[1]); o.u[1] = pack2(a[2], a[3]);
            o.u[2] = pack2(b2[0], b2[1]); o.u[3] = pack2(b2[2], b2[3]);
            *(bf8*)&xs[row][((c ^ row) & 31) * 8] = o.v;
        }
    }
    __syncthreads();

    const int t24 = grp * 4 + w;          // 0..23
    const int mat = t24 >> 3;             // 0=q 1=k 2=v
    const int dt = t24 & 7;
    const int head = dt >> 1, d32 = dt & 1;

    const __hip_bfloat16* wb = wpk + (size_t)((mat * 8 + dt) * 16) * 512 + (size_t)lane * 8;
    bf8 wf[16];
    #pragma unroll
    for (int ks = 0; ks < 16; ++ks) wf[ks] = *(const bf8*)&wb[ks * 512];

    f16v acc;
    #pragma unroll
    for (int r = 0; r < 16; ++r) acc[r] = 0.0f;

    if (mat < 2) {
        #pragma unroll
        for (int ks = 0; ks < 16; ++ks) {
            const bf8 xf = *(const bf8*)&xs[l5][(((ks * 2 + hi) ^ l5) & 31) * 8];
            acc = __builtin_amdgcn_mfma_f32_32x32x16_bf16(wf[ks], xf, acc, 0, 0, 0);
        }
    } else {
        #pragma unroll
        for (int ks = 0; ks < 16; ++ks) {
            const bf8 xf = *(const bf8*)&xs[l5][(((ks * 2 + hi) ^ l5) & 31) * 8];
            acc = __builtin_amdgcn_mfma_f32_32x32x16_bf16(xf, wf[ks], acc, 0, 0, 0);
        }
    }

    const float QSCALE = 0.18033688011112042f;   // 0.125 * log2(e)
    if (mat == 0) {
        f4 b4[4];
        #pragma unroll
        for (int j = 0; j < 4; ++j)
            b4[j] = *(const f4*)&bq[head * 64 + d32 * 32 + j * 8 + 4 * hi];
        #pragma unroll
        for (int r = 0; r < 16; ++r) acc[r] = (acc[r] + b4[r >> 2][r & 3]) * QSCALE;
    } else if (mat == 1) {
        f4 b4[4];
        #pragma unroll
        for (int j = 0; j < 4; ++j)
            b4[j] = *(const f4*)&bk[head * 64 + d32 * 32 + j * 8 + 4 * hi];
        #pragma unroll
        for (int r = 0; r < 16; ++r) acc[r] += b4[r >> 2][r & 3];
    } else {
        const float bn = bv[head * 64 + d32 * 32 + l5];
        #pragma unroll
        for (int r = 0; r < 16; ++r) acc[r] += bn;
    }

    unsigned wd[8];
    #pragma unroll
    for (int i = 0; i < 8; ++i) wd[i] = pack2(acc[2 * i], acc[2 * i + 1]);
    const unsigned e0 = (unsigned)__shfl_xor((int)(hi ? wd[0] : wd[2]), 32, 64);
    const unsigned e1 = (unsigned)__shfl_xor((int)(hi ? wd[1] : wd[3]), 32, 64);
    const unsigned e2 = (unsigned)__shfl_xor((int)(hi ? wd[4] : wd[6]), 32, 64);
    const unsigned e3 = (unsigned)__shfl_xor((int)(hi ? wd[5] : wd[7]), 32, 64);
    union { unsigned u[4]; bf8 v; } fa, fb;
    if (hi == 0) {
        fa.u[0] = wd[0]; fa.u[1] = wd[1]; fa.u[2] = e0; fa.u[3] = e1;
        fb.u[0] = wd[4]; fb.u[1] = wd[5]; fb.u[2] = e2; fb.u[3] = e3;
    } else {
        fa.u[0] = e0; fa.u[1] = e1; fa.u[2] = wd[2]; fa.u[3] = wd[3];
        fb.u[0] = e2; fb.u[1] = e3; fb.u[2] = wd[6]; fb.u[3] = wd[7];
    }

    const int hd = bidx * NH + head;
    if (mat == 0) {
        __hip_bfloat16* qb = qfrag + (size_t)hd * QFRAG_PER_HEAD;
        *(bf8*)&qb[((size_t)(stl * 6 + d32 * 2 + 0) * 64 + lane) * 8] = fa.v;
        *(bf8*)&qb[((size_t)(stl * 6 + d32 * 2 + 1) * 64 + lane) * 8] = fb.v;
    } else if (mat == 1) {
        __hip_bfloat16* kb = kfrag + (size_t)hd * KFRAG_PER_HEAD;
        *(bf8*)&kb[((size_t)(tkv * 12 + d32 * 4 + hs) * 64 + lane) * 8] = fa.v;
        *(bf8*)&kb[((size_t)(tkv * 12 + d32 * 4 + 2 + hs) * 64 + lane) * 8] = fb.v;
    } else {
        __hip_bfloat16* vb = vfrag + (size_t)hd * VFRAG_PER_HEAD;
        const int ja = ((stl * 2 + 0) & 3) * 2 + d32;
        const int jb = ((stl * 2 + 1) & 3) * 2 + d32;
        *(bf8*)&vb[((size_t)(tkv * 8 + ja) * 64 + lane) * 8] = fa.v;
        *(bf8*)&vb[((size_t)(tkv * 8 + jb) * 64 + lane) * 8] = fb.v;
    }

    if (grp == 0) {
        const int hh = w;
        const int hd2 = bidx * NH + hh;
        __hip_bfloat16* qb = qfrag + (size_t)hd2 * QFRAG_PER_HEAD;
        __hip_bfloat16* kb = kfrag + (size_t)hd2 * KFRAG_PER_HEAD;
        u4v z; z[0] = 0; z[1] = 0; z[2] = 0; z[3] = 0;
        *(u4v*)&qb[((size_t)(stl * 6 + 4) * 64 + lane) * 8] = z;
        *(u4v*)&qb[((size_t)(stl * 6 + 5) * 64 + lane) * 8] = z;
        *(u4v*)&kb[((size_t)(tkv * 12 + 8 + hs) * 64 + lane) * 8] = z;
        *(u4v*)&kb[((size_t)(tkv * 12 + 10 + hs) * 64 + lane) * 8] = z;
        asm volatile("s_waitcnt vmcnt(0)" ::: "memory");
        if (hi == 0) {
            const int cg = gid[codons[bidx * SS + stl * 32 + l5] & 63];
            const float bl2e = *betaP;
            const int lt = ((cg >> 3) & 1) * 32 + l5;
            qb[((size_t)(stl * 6 + 4 + (cg >> 4)) * 64 + lt) * 8 + (cg & 7)] =
                __float2bfloat16(bl2e);
            kb[((size_t)(tkv * 12 + 8 + (cg >> 4) * 2 + hs) * 64 + lt) * 8 + (cg & 7)] =
                __float2bfloat16(1.0f);
        }
    }
}

// ---------------------------------------------------------------------------
// Flash attention: 64 q-rows PER WAVE (2 q-tiles), one KV quarter per wave.
// Doubles arithmetic intensity vs R6 (same 20KB K/V feeds 40 MFMA).
// Barrier-free main loop; scores regs reused across the two q-tiles.
// grid 512 = 64 qgroups x 8 bh (XCD-pinned).
// ---------------------------------------------------------------------------
__global__ __launch_bounds__(256, 2)
void attn_kernel(const __hip_bfloat16* __restrict__ qfrag,
                 const __hip_bfloat16* __restrict__ kfrag,
                 const __hip_bfloat16* __restrict__ vfrag,
                 __hip_bfloat16* __restrict__ aoutb)
{
    const int bid = blockIdx.x;           // 512 blocks
    const int bh = bid & 7;
    const int b = bh >> 2, h = bh & 3;
    const int qg = bid >> 3;              // 0..63 -> rows [qg*64, qg*64+64)
    const int tid = threadIdx.x;
    const int w = tid >> 6;               // KV quarter 0..3
    const int lane = tid & 63;
    const int q5 = lane & 31;
    const int hi = lane >> 5;

    __shared__ float o_sh[4][64][69];
    __shared__ float l_sh[4][64];

    const __hip_bfloat16* kf_base = kfrag + (size_t)(b * NH + h) * KFRAG_PER_HEAD + lane * 8;
    const __hip_bfloat16* vf_base = vfrag + (size_t)(b * NH + h) * VFRAG_PER_HEAD + lane * 8;

    // ---- Q fragments for both tiles (stl = 2qg, 2qg+1)
    const __hip_bfloat16* qb = qfrag + (size_t)(b * NH + h) * QFRAG_PER_HEAD
                               + ((size_t)(qg * 2) * 6 * 64 + lane) * 8;
    bf8 qf0[6], qf1[6];
    #pragma unroll
    for (int ks = 0; ks < 6; ++ks) {
        qf0[ks] = *(const bf8*)&qb[ks * 512];
        qf1[ks] = *(const bf8*)&qb[3072 + ks * 512];
    }

    f16v oacc00, oacc01, oacc10, oacc11;
    #pragma unroll
    for (int r = 0; r < 16; ++r) {
        oacc00[r] = 0.0f; oacc01[r] = 0.0f; oacc10[r] = 0.0f; oacc11[r] = 0.0f;
    }
    float lrun0 = 0.0f, lrun1 = 0.0f;

    bf8 kf[12];
    const int tt0 = w * 16;

    auto loadK = [&](int tt) {
        const __hip_bfloat16* p = kf_base + (size_t)tt * (12 * 64 * 8);
        #pragma unroll
        for (int j = 0; j < 12; ++j) kf[j] = *(const bf8*)&p[j * 512];
    };

    // pack-exchange: scores (sA,sB) -> 4 PV B-operand fragments
    auto packP = [&](const f16v& sA, const f16v& sB, bf8 (&pfv)[4]) {
        unsigned dwv[2][4][2];
        #pragma unroll
        for (int j = 0; j < 4; ++j)
            #pragma unroll
            for (int c = 0; c < 2; ++c) {
                dwv[0][j][c] = pack2(sA[j * 4 + 2 * c], sA[j * 4 + 2 * c + 1]);
                dwv[1][j][c] = pack2(sB[j * 4 + 2 * c], sB[j * 4 + 2 * c + 1]);
            }
        unsigned rc[2][2][2];
        #pragma unroll
        for (int t2 = 0; t2 < 2; ++t2)
            #pragma unroll
            for (int k1 = 0; k1 < 2; ++k1)
                #pragma unroll
                for (int c = 0; c < 2; ++c) {
                    const unsigned snd = hi ? dwv[t2][2 * k1][c] : dwv[t2][2 * k1 + 1][c];
                    rc[t2][k1][c] = (unsigned)__shfl_xor((int)snd, 32, 64);
                }
        #pragma unroll
        for (int ks = 0; ks < 4; ++ks) {
            const int t2 = ks >> 1, k1 = ks & 1;
            union { unsigned u[4]; bf8 v; } pu;
            pu.u[0] = hi ? rc[t2][k1][0] : dwv[t2][2 * k1][0];
            pu.u[1] = hi ? rc[t2][k1][1] : dwv[t2][2 * k1][1];
            pu.u[2] = hi ? dwv[t2][2 * k1 + 1][0] : rc[t2][k1][0];
            pu.u[3] = hi ? dwv[t2][2 * k1 + 1][1] : rc[t2][k1][1];
            pfv[ks] = pu.v;
        }
    };

    loadK(tt0);

    #pragma unroll 1
    for (int t = 0; t < 16; ++t) {
        const int tt = tt0 + t;

        // V for this tile (consumed ~600cyc later in PV)
        bf8 vf[8];
        const __hip_bfloat16* vp = vf_base + (size_t)tt * (8 * 64 * 8);
        #pragma unroll
        for (int j = 0; j < 8; ++j) vf[j] = *(const bf8*)&vp[j * 512];

        // ---- QK^T tile0
        f16v sA, sB;
        #pragma unroll
        for (int r = 0; r < 16; ++r) { sA[r] = 0.0f; sB[r] = 0.0f; }
        __builtin_amdgcn_s_setprio(1);
        #pragma unroll
        for (int ks = 0; ks < 6; ++ks) {
            sA = __builtin_amdgcn_mfma_f32_32x32x16_bf16(kf[ks * 2 + 0], qf0[ks], sA, 0, 0, 0);
            sB = __builtin_amdgcn_mfma_f32_32x32x16_bf16(kf[ks * 2 + 1], qf0[ks], sB, 0, 0, 0);
        }
        __builtin_amdgcn_s_setprio(0);

        float ls0 = 0.0f;
        #pragma unroll
        for (int r = 0; r < 16; ++r) { sA[r] = fast_exp2(sA[r]); ls0 += sA[r]; }
        #pragma unroll
        for (int r = 0; r < 16; ++r) { sB[r] = fast_exp2(sB[r]); ls0 += sB[r]; }
        lrun0 += ls0;
        bf8 pfv0[4];
        packP(sA, sB, pfv0);

        // ---- QK^T tile1 (reuse sA/sB)
        #pragma unroll
        for (int r = 0; r < 16; ++r) { sA[r] = 0.0f; sB[r] = 0.0f; }
        __builtin_amdgcn_s_setprio(1);
        #pragma unroll
        for (int ks = 0; ks < 6; ++ks) {
            sA = __builtin_amdgcn_mfma_f32_32x32x16_bf16(kf[ks * 2 + 0], qf1[ks], sA, 0, 0, 0);
            sB = __builtin_amdgcn_mfma_f32_32x32x16_bf16(kf[ks * 2 + 1], qf1[ks], sB, 0, 0, 0);
        }
        __builtin_amdgcn_s_setprio(0);

        // kf free -> prefetch next K tile (covered by exp1/pack1 + PV)
        if (t + 1 < 16) loadK(tt + 1);

        float ls1 = 0.0f;
        #pragma unroll
        for (int r = 0; r < 16; ++r) { sA[r] = fast_exp2(sA[r]); ls1 += sA[r]; }
        #pragma unroll
        for (int r = 0; r < 16; ++r) { sB[r] = fast_exp2(sB[r]); ls1 += sB[r]; }
        lrun1 += ls1;
        bf8 pfv1[4];
        packP(sA, sB, pfv1);

        // ---- PV for both tiles
        __builtin_amdgcn_s_setprio(1);
        #pragma unroll
        for (int ks = 0; ks < 4; ++ks) {
            oacc00 = __builtin_amdgcn_mfma_f32_32x32x16_bf16(vf[ks * 2 + 0], pfv0[ks], oacc00, 0, 0, 0);
            oacc01 = __builtin_amdgcn_mfma_f32_32x32x16_bf16(vf[ks * 2 + 1], pfv0[ks], oacc01, 0, 0, 0);
            oacc10 = __builtin_amdgcn_mfma_f32_32x32x16_bf16(vf[ks * 2 + 0], pfv1[ks], oacc10, 0, 0, 0);
            oacc11 = __builtin_amdgcn_mfma_f32_32x32x16_bf16(vf[ks * 2 + 1], pfv1[ks], oacc11, 0, 0, 0);
        }
        __builtin_amdgcn_s_setprio(0);
    }

    // ---- per-warp partials -> LDS
    const float ltot0 = lrun0 + __shfl_xor(lrun0, 32, 64);
    const float ltot1 = lrun1 + __shfl_xor(lrun1, 32, 64);
    #pragma unroll
    for (int r = 0; r < 16; ++r) {
        const int d = (r & 3) + 8 * (r >> 2) + 4 * hi;
        o_sh[w][q5][d] = oacc00[r];
        o_sh[w][q5][32 + d] = oacc01[r];
        o_sh[w][32 + q5][d] = oacc10[r];
        o_sh[w][32 + q5][32 + d] = oacc11[r];
    }
    if (hi == 0) { l_sh[w][q5] = ltot0; l_sh[w][32 + q5] = ltot1; }
    __syncthreads();

    // ---- cooperative merge: 256 threads over 64 rows x 64 dims
    const int row = tid >> 2;
    const int d0 = (tid & 3) * 16;
    const float inv = 1.0f / (l_sh[0][row] + l_sh[1][row] + l_sh[2][row] + l_sh[3][row]);
    float vals[16];
    #pragma unroll
    for (int j = 0; j < 16; ++j)
        vals[j] = (o_sh[0][row][d0 + j] + o_sh[1][row][d0 + j]
                 + o_sh[2][row][d0 + j] + o_sh[3][row][d0 + j]) * inv;
    union { unsigned u[4]; bf8 v; } ov0, ov1;
    ov0.u[0] = pack2(vals[0], vals[1]);   ov0.u[1] = pack2(vals[2], vals[3]);
    ov0.u[2] = pack2(vals[4], vals[5]);   ov0.u[3] = pack2(vals[6], vals[7]);
    ov1.u[0] = pack2(vals[8], vals[9]);   ov1.u[1] = pack2(vals[10], vals[11]);
    ov1.u[2] = pack2(vals[12], vals[13]); ov1.u[3] = pack2(vals[14], vals[15]);
    __hip_bfloat16* dst = &aoutb[((size_t)b * SS + qg * 64 + row) * HID + h * HD + d0];
    *(bf8*)&dst[0] = ov0.v;
    *(bf8*)&dst[8] = ov1.v;
}

// ---------------------------------------------------------------------------
// Output projection via MFMA (unchanged from R6).
// ---------------------------------------------------------------------------
__global__ __launch_bounds__(256)
void out_proj_kernel(const __hip_bfloat16* __restrict__ aoutb,
                     const __hip_bfloat16* __restrict__ wpk,
                     const float* __restrict__ bo, float* __restrict__ out)
{
    const int bid = blockIdx.x;
    const int stile = bid >> 1, grp = bid & 1;
    const int tid = threadIdx.x;
    const int w = tid >> 6, lane = tid & 63, hi = lane >> 5, l5 = lane & 31;

    __shared__ __hip_bfloat16 xs[32][256];
    {
        const int r0 = tid >> 5, c = tid & 31;
        #pragma unroll
        for (int it = 0; it < 4; ++it) {
            const int row = r0 + it * 8;
            const bf8 v = *(const bf8*)&aoutb[(size_t)(stile * 32 + row) * HID + c * 8];
            *(bf8*)&xs[row][((c ^ row) & 31) * 8] = v;
        }
    }
    __syncthreads();

    const int nt = grp * 4 + w;           // 0..7
    const __hip_bfloat16* wb = wpk + (size_t)((3 * 8 + nt) * 16) * 512 + (size_t)lane * 8;
    bf8 wf[16];
    #pragma unroll
    for (int ks = 0; ks < 16; ++ks) wf[ks] = *(const bf8*)&wb[ks * 512];

    f16v acc;
    #pragma unroll
    for (int r = 0; r < 16; ++r) acc[r] = 0.0f;
    #pragma unroll
    for (int ks = 0; ks < 16; ++ks) {
        const bf8 xf = *(const bf8*)&xs[l5][(((ks * 2 + hi) ^ l5) & 31) * 8];
        acc = __builtin_amdgcn_mfma_f32_32x32x16_bf16(xf, wf[ks], acc, 0, 0, 0);
    }

    const float bn = bo[nt * 32 + l5];
    #pragma unroll
    for (int r = 0; r < 16; ++r) {
        const int sloc = (r & 3) + 8 * (r >> 2) + 4 * hi;
        out[(size_t)(stile * 32 + sloc) * HID + nt * 32 + l5] = acc[r] + bn;
    }
}

extern "C" void kernel_launch(void* const* d_in, const int* in_sizes, int n_in,
                              void* d_out, int out_size, void* d_ws, size_t ws_size,
                              hipStream_t stream)
{
    (void)in_sizes; (void)n_in; (void)out_size; (void)ws_size;
    const float* x        = (const float*)d_in[0];
    const int*   codons   = (const int*)d_in[1];
    const float* syn_bias = (const float*)d_in[2];
    const float* wq = (const float*)d_in[3];
    const float* bq = (const float*)d_in[4];
    const float* wk = (const float*)d_in[5];
    const float* bk = (const float*)d_in[6];
    const float* wv = (const float*)d_in[7];
    const float* bv = (const float*)d_in[8];
    const float* wo = (const float*)d_in[9];
    const float* bo = (const float*)d_in[10];
    float* out = (float*)d_out;

    char* ws = (char*)d_ws;
    int*   gid   = (int*)(ws);                                  // 256 B
    float* betaP = (float*)(ws + 256);                          // 4 B
    __hip_bfloat16* wpk   = (__hip_bfloat16*)(ws + 4096);       // 512 KB
    __hip_bfloat16* qfrag = (__hip_bfloat16*)(ws + (size_t)1048576u);    // 6 MB
    __hip_bfloat16* kfrag = (__hip_bfloat16*)(ws + (size_t)7340032u);    // 6 MB
    __hip_bfloat16* vfrag = (__hip_bfloat16*)(ws + (size_t)13631488u);   // 4 MB
    __hip_bfloat16* aoutb = (__hip_bfloat16*)(ws + (size_t)17825792u);   // 4 MB

    setup_kernel<<<1, 64, 0, stream>>>(syn_bias, gid, betaP);
    pack_w_kernel<<<128, 256, 0, stream>>>(wq, wk, wv, wo, wpk);
    qkv_mfma_kernel<<<1536, 256, 0, stream>>>(x, wpk, bq, bk, bv, codons, gid, betaP,
                                              qfrag, kfrag, vfrag);
    attn_kernel<<<512, 256, 0, stream>>>(qfrag, kfrag, vfrag, aoutb);
    out_proj_kernel<<<512, 256, 0, stream>>>(aoutb, wpk, bo, out);
}

// Round 8
// 84.168 us; speedup vs baseline: 1.2211x; 1.2211x over previous
//
#include <hip/hip_runtime.h>
#include <hip/hip_bf16.h>

#define NH 4
#define HD 64
#define HID 256
#define SS 4096

#define QFRAG_PER_HEAD (128 * 6 * 64 * 8)   // 393216 elems
#define KFRAG_PER_HEAD (64 * 12 * 64 * 8)   // 393216 elems
#define VFRAG_PER_HEAD (64 * 8 * 64 * 8)    // 262144 elems

typedef float f4 __attribute__((ext_vector_type(4)));
typedef float f16v __attribute__((ext_vector_type(16)));
typedef short bf8 __attribute__((ext_vector_type(8)));   // 8 bf16
typedef unsigned int u4v __attribute__((ext_vector_type(4)));

static __device__ __forceinline__ float fast_exp2(float x) {
#if __has_builtin(__builtin_amdgcn_exp2f)
    return __builtin_amdgcn_exp2f(x);
#else
    float r; asm("v_exp_f32 %0, %1" : "=v"(r) : "v"(x)); return r;
#endif
}

static __device__ __forceinline__ unsigned pack2(float a, float b) {
    unsigned ua = (unsigned)__bfloat16_as_ushort(__float2bfloat16(a));
    unsigned ub = (unsigned)__bfloat16_as_ushort(__float2bfloat16(b));
    return ua | (ub << 16);
}

// ---------------------------------------------------------------------------
// Setup: codon->group-id map + beta*log2e.
// ---------------------------------------------------------------------------
__global__ void setup_kernel(const float* __restrict__ syn,
                             int* __restrict__ gid, float* __restrict__ betaP)
{
    const int lane = threadIdx.x;          // 0..63
    int rep = 64;
    for (int j = 63; j >= 0; --j)
        if (syn[lane * 64 + j] != 0.0f) rep = j;
    if (rep == 64) rep = lane;
    unsigned long long m = __ballot(rep == lane);
    int id = (int)__popcll(m & ((2ull << rep) - 1ull)) - 1;
    if (id < 0) id = 0;
    gid[lane] = id;                                 // 0..20
    if (lane == 0) *betaP = syn[0] * 1.44269504088896f;
}

// ---------------------------------------------------------------------------
// Pack wq/wk/wv/wo into MFMA fragment-major bf16.
// ---------------------------------------------------------------------------
__global__ __launch_bounds__(256)
void pack_w_kernel(const float* __restrict__ wq, const float* __restrict__ wk,
                   const float* __restrict__ wv, const float* __restrict__ wo,
                   __hip_bfloat16* __restrict__ wpk)
{
    const int t = blockIdx.x * 256 + threadIdx.x;   // 0..32767
    const int mat = t >> 13;
    const int r = t & 8191;
    const int dt = r >> 10, ks = (r >> 6) & 15, lane = r & 63;
    const float* w = (mat == 0) ? wq : (mat == 1) ? wk : (mat == 2) ? wv : wo;
    const int row = dt * 32 + (lane & 31);
    const int col = ks * 16 + (lane >> 5) * 8;
    const f4 a = *(const f4*)&w[(size_t)row * 256 + col];
    const f4 b = *(const f4*)&w[(size_t)row * 256 + col + 4];
    union { unsigned u[4]; bf8 v; } o;
    o.u[0] = pack2(a[0], a[1]); o.u[1] = pack2(a[2], a[3]);
    o.u[2] = pack2(b[0], b[1]); o.u[3] = pack2(b[2], b[3]);
    *(bf8*)&wpk[(size_t)t * 8] = o.v;
}

// ---------------------------------------------------------------------------
// QKV projection via MFMA (unchanged from R6).
// ---------------------------------------------------------------------------
__global__ __launch_bounds__(256)
void qkv_mfma_kernel(const float* __restrict__ x,
                     const __hip_bfloat16* __restrict__ wpk,
                     const float* __restrict__ bq, const float* __restrict__ bk,
                     const float* __restrict__ bv,
                     const int* __restrict__ codons,
                     const int* __restrict__ gid, const float* __restrict__ betaP,
                     __hip_bfloat16* __restrict__ qfrag,
                     __hip_bfloat16* __restrict__ kfrag,
                     __hip_bfloat16* __restrict__ vfrag)
{
    const int bid = blockIdx.x;
    const int stile = bid / 6;            // 0..255
    const int grp = bid % 6;
    const int tid = threadIdx.x;
    const int w = tid >> 6, lane = tid & 63, hi = lane >> 5, l5 = lane & 31;

    const int bidx = stile >> 7;
    const int stl = stile & 127;
    const int hs = stl & 1, tkv = stl >> 1;

    __shared__ __hip_bfloat16 xs[32][256];

    {
        const int r0 = tid >> 5, c = tid & 31;
        #pragma unroll
        for (int it = 0; it < 4; ++it) {
            const int row = r0 + it * 8;
            const f4 a = *(const f4*)&x[(size_t)(stile * 32 + row) * HID + c * 8];
            const f4 b2 = *(const f4*)&x[(size_t)(stile * 32 + row) * HID + c * 8 + 4];
            union { unsigned u[4]; bf8 v; } o;
            o.u[0] = pack2(a[0], a[1]); o.u[1] = pack2(a[2], a[3]);
            o.u[2] = pack2(b2[0], b2[1]); o.u[3] = pack2(b2[2], b2[3]);
            *(bf8*)&xs[row][((c ^ row) & 31) * 8] = o.v;
        }
    }
    __syncthreads();

    const int t24 = grp * 4 + w;          // 0..23
    const int mat = t24 >> 3;             // 0=q 1=k 2=v
    const int dt = t24 & 7;
    const int head = dt >> 1, d32 = dt & 1;

    const __hip_bfloat16* wb = wpk + (size_t)((mat * 8 + dt) * 16) * 512 + (size_t)lane * 8;
    bf8 wf[16];
    #pragma unroll
    for (int ks = 0; ks < 16; ++ks) wf[ks] = *(const bf8*)&wb[ks * 512];

    f16v acc;
    #pragma unroll
    for (int r = 0; r < 16; ++r) acc[r] = 0.0f;

    if (mat < 2) {
        #pragma unroll
        for (int ks = 0; ks < 16; ++ks) {
            const bf8 xf = *(const bf8*)&xs[l5][(((ks * 2 + hi) ^ l5) & 31) * 8];
            acc = __builtin_amdgcn_mfma_f32_32x32x16_bf16(wf[ks], xf, acc, 0, 0, 0);
        }
    } else {
        #pragma unroll
        for (int ks = 0; ks < 16; ++ks) {
            const bf8 xf = *(const bf8*)&xs[l5][(((ks * 2 + hi) ^ l5) & 31) * 8];
            acc = __builtin_amdgcn_mfma_f32_32x32x16_bf16(xf, wf[ks], acc, 0, 0, 0);
        }
    }

    const float QSCALE = 0.18033688011112042f;   // 0.125 * log2(e)
    if (mat == 0) {
        f4 b4[4];
        #pragma unroll
        for (int j = 0; j < 4; ++j)
            b4[j] = *(const f4*)&bq[head * 64 + d32 * 32 + j * 8 + 4 * hi];
        #pragma unroll
        for (int r = 0; r < 16; ++r) acc[r] = (acc[r] + b4[r >> 2][r & 3]) * QSCALE;
    } else if (mat == 1) {
        f4 b4[4];
        #pragma unroll
        for (int j = 0; j < 4; ++j)
            b4[j] = *(const f4*)&bk[head * 64 + d32 * 32 + j * 8 + 4 * hi];
        #pragma unroll
        for (int r = 0; r < 16; ++r) acc[r] += b4[r >> 2][r & 3];
    } else {
        const float bn = bv[head * 64 + d32 * 32 + l5];
        #pragma unroll
        for (int r = 0; r < 16; ++r) acc[r] += bn;
    }

    unsigned wd[8];
    #pragma unroll
    for (int i = 0; i < 8; ++i) wd[i] = pack2(acc[2 * i], acc[2 * i + 1]);
    const unsigned e0 = (unsigned)__shfl_xor((int)(hi ? wd[0] : wd[2]), 32, 64);
    const unsigned e1 = (unsigned)__shfl_xor((int)(hi ? wd[1] : wd[3]), 32, 64);
    const unsigned e2 = (unsigned)__shfl_xor((int)(hi ? wd[4] : wd[6]), 32, 64);
    const unsigned e3 = (unsigned)__shfl_xor((int)(hi ? wd[5] : wd[7]), 32, 64);
    union { unsigned u[4]; bf8 v; } fa, fb;
    if (hi == 0) {
        fa.u[0] = wd[0]; fa.u[1] = wd[1]; fa.u[2] = e0; fa.u[3] = e1;
        fb.u[0] = wd[4]; fb.u[1] = wd[5]; fb.u[2] = e2; fb.u[3] = e3;
    } else {
        fa.u[0] = e0; fa.u[1] = e1; fa.u[2] = wd[2]; fa.u[3] = wd[3];
        fb.u[0] = e2; fb.u[1] = e3; fb.u[2] = wd[6]; fb.u[3] = wd[7];
    }

    const int hd = bidx * NH + head;
    if (mat == 0) {
        __hip_bfloat16* qb = qfrag + (size_t)hd * QFRAG_PER_HEAD;
        *(bf8*)&qb[((size_t)(stl * 6 + d32 * 2 + 0) * 64 + lane) * 8] = fa.v;
        *(bf8*)&qb[((size_t)(stl * 6 + d32 * 2 + 1) * 64 + lane) * 8] = fb.v;
    } else if (mat == 1) {
        __hip_bfloat16* kb = kfrag + (size_t)hd * KFRAG_PER_HEAD;
        *(bf8*)&kb[((size_t)(tkv * 12 + d32 * 4 + hs) * 64 + lane) * 8] = fa.v;
        *(bf8*)&kb[((size_t)(tkv * 12 + d32 * 4 + 2 + hs) * 64 + lane) * 8] = fb.v;
    } else {
        __hip_bfloat16* vb = vfrag + (size_t)hd * VFRAG_PER_HEAD;
        const int ja = ((stl * 2 + 0) & 3) * 2 + d32;
        const int jb = ((stl * 2 + 1) & 3) * 2 + d32;
        *(bf8*)&vb[((size_t)(tkv * 8 + ja) * 64 + lane) * 8] = fa.v;
        *(bf8*)&vb[((size_t)(tkv * 8 + jb) * 64 + lane) * 8] = fb.v;
    }

    if (grp == 0) {
        const int hh = w;
        const int hd2 = bidx * NH + hh;
        __hip_bfloat16* qb = qfrag + (size_t)hd2 * QFRAG_PER_HEAD;
        __hip_bfloat16* kb = kfrag + (size_t)hd2 * KFRAG_PER_HEAD;
        u4v z; z[0] = 0; z[1] = 0; z[2] = 0; z[3] = 0;
        *(u4v*)&qb[((size_t)(stl * 6 + 4) * 64 + lane) * 8] = z;
        *(u4v*)&qb[((size_t)(stl * 6 + 5) * 64 + lane) * 8] = z;
        *(u4v*)&kb[((size_t)(tkv * 12 + 8 + hs) * 64 + lane) * 8] = z;
        *(u4v*)&kb[((size_t)(tkv * 12 + 10 + hs) * 64 + lane) * 8] = z;
        asm volatile("s_waitcnt vmcnt(0)" ::: "memory");
        if (hi == 0) {
            const int cg = gid[codons[bidx * SS + stl * 32 + l5] & 63];
            const float bl2e = *betaP;
            const int lt = ((cg >> 3) & 1) * 32 + l5;
            qb[((size_t)(stl * 6 + 4 + (cg >> 4)) * 64 + lt) * 8 + (cg & 7)] =
                __float2bfloat16(bl2e);
            kb[((size_t)(tkv * 12 + 8 + (cg >> 4) * 2 + hs) * 64 + lt) * 8 + (cg & 7)] =
                __float2bfloat16(1.0f);
        }
    }
}

// ---------------------------------------------------------------------------
// Flash attention: LDS-shared K/V. Block = 4 waves x own 32-row q-tile
// (128 rows), all consuming the same 64-key tile staged in LDS (dbuf,
// reg-staged T14 pipeline, 1 barrier/tile). KV halved -> 512 blocks = 2/CU;
// bid&7 pins each (b,h) to one XCD. Halves merged later (no-max exp2 ->
// partials directly summable). Writes bf16 partial O + f32 l-sums.
// ---------------------------------------------------------------------------
__global__ __launch_bounds__(256, 2)
void attn_kernel(const __hip_bfloat16* __restrict__ qfrag,
                 const __hip_bfloat16* __restrict__ kfrag,
                 const __hip_bfloat16* __restrict__ vfrag,
                 __hip_bfloat16* __restrict__ po0,
                 __hip_bfloat16* __restrict__ po1,
                 float* __restrict__ ls0,
                 float* __restrict__ ls1)
{
    const int bid = blockIdx.x;           // 512 blocks
    const int bh = bid & 7;               // XCD-pinned (b,h)
    const int b = bh >> 2, h = bh & 3;
    const int idx = bid >> 3;             // 0..63
    const int half = idx & 1;
    const int qg = idx >> 1;              // 0..31 -> rows [qg*128, +128)
    const int tid = threadIdx.x;
    const int w = tid >> 6;               // wave -> q-subtile
    const int lane = tid & 63;
    const int q5 = lane & 31;
    const int hi = lane >> 5;

    __shared__ __align__(16) char smem[40960];   // 2 x 20KB KV tile (K12+V8)
    __shared__ float l_sh[128];

    const char* kT = (const char*)(kfrag + (size_t)(b * NH + h) * KFRAG_PER_HEAD);
    const char* vT = (const char*)(vfrag + (size_t)(b * NH + h) * VFRAG_PER_HEAD);

    // ---- Q fragments: wave w owns stile qg*4+w
    const int stl = qg * 4 + w;
    const __hip_bfloat16* qb = qfrag + (size_t)(b * NH + h) * QFRAG_PER_HEAD
                               + ((size_t)stl * 6 * 64 + lane) * 8;
    bf8 qf[6];
    #pragma unroll
    for (int ks = 0; ks < 6; ++ks) qf[ks] = *(const bf8*)&qb[ks * 512];

    f16v oacc0, oacc1;
    #pragma unroll
    for (int r = 0; r < 16; ++r) { oacc0[r] = 0.0f; oacc1[r] = 0.0f; }
    float lrun = 0.0f;

    const int w5 = w * 5;                 // this wave stages chunks w5..w5+4 (of 20)
    bf8 g[5];

    auto loadG = [&](int tt) {
        #pragma unroll
        for (int c = 0; c < 5; ++c) {
            const int id = w5 + c;
            const char* src = (id < 12)
                ? kT + (size_t)tt * 12288 + (size_t)id * 1024
                : vT + (size_t)tt * 8192 + (size_t)(id - 12) * 1024;
            g[c] = *(const bf8*)(src + lane * 16);
        }
    };
    auto writeL = [&](int buf) {
        #pragma unroll
        for (int c = 0; c < 5; ++c) {
            const int id = w5 + c;
            *(bf8*)&smem[buf * 20480 + id * 1024 + lane * 16] = g[c];
        }
    };

    const int tt0 = half * 32;
    loadG(tt0);
    writeL(0);
    __syncthreads();

    int cur = 0;
    #pragma unroll 1
    for (int t = 0; t < 32; ++t) {
        if (t + 1 < 32) loadG(tt0 + t + 1);   // issue early (T14)

        const char* kb = smem + cur * 20480 + lane * 16;

        // ---- QK^T (swapped): D[key][q]
        f16v sA, sB;
        #pragma unroll
        for (int r = 0; r < 16; ++r) { sA[r] = 0.0f; sB[r] = 0.0f; }
        __builtin_amdgcn_s_setprio(1);
        #pragma unroll
        for (int ks = 0; ks < 6; ++ks) {
            const bf8 k0 = *(const bf8*)(kb + (2 * ks) * 1024);
            const bf8 k1 = *(const bf8*)(kb + (2 * ks + 1) * 1024);
            sA = __builtin_amdgcn_mfma_f32_32x32x16_bf16(k0, qf[ks], sA, 0, 0, 0);
            sB = __builtin_amdgcn_mfma_f32_32x32x16_bf16(k1, qf[ks], sB, 0, 0, 0);
        }
        __builtin_amdgcn_s_setprio(0);

        // ---- p = 2^s
        float ls = 0.0f;
        #pragma unroll
        for (int r = 0; r < 16; ++r) { sA[r] = fast_exp2(sA[r]); ls += sA[r]; }
        #pragma unroll
        for (int r = 0; r < 16; ++r) { sB[r] = fast_exp2(sB[r]); ls += sB[r]; }
        lrun += ls;

        // ---- pack-exchange -> PV B fragments
        unsigned dwv[2][4][2];
        #pragma unroll
        for (int j = 0; j < 4; ++j)
            #pragma unroll
            for (int c = 0; c < 2; ++c) {
                dwv[0][j][c] = pack2(sA[j * 4 + 2 * c], sA[j * 4 + 2 * c + 1]);
                dwv[1][j][c] = pack2(sB[j * 4 + 2 * c], sB[j * 4 + 2 * c + 1]);
            }
        unsigned rc[2][2][2];
        #pragma unroll
        for (int t2 = 0; t2 < 2; ++t2)
            #pragma unroll
            for (int k1 = 0; k1 < 2; ++k1)
                #pragma unroll
                for (int c = 0; c < 2; ++c) {
                    const unsigned snd = hi ? dwv[t2][2 * k1][c] : dwv[t2][2 * k1 + 1][c];
                    rc[t2][k1][c] = (unsigned)__shfl_xor((int)snd, 32, 64);
                }
        bf8 pfv[4];
        #pragma unroll
        for (int ks = 0; ks < 4; ++ks) {
            const int t2 = ks >> 1, k1 = ks & 1;
            union { unsigned u[4]; bf8 v; } pu;
            pu.u[0] = hi ? rc[t2][k1][0] : dwv[t2][2 * k1][0];
            pu.u[1] = hi ? rc[t2][k1][1] : dwv[t2][2 * k1][1];
            pu.u[2] = hi ? dwv[t2][2 * k1 + 1][0] : rc[t2][k1][0];
            pu.u[3] = hi ? dwv[t2][2 * k1 + 1][1] : rc[t2][k1][1];
            pfv[ks] = pu.v;
        }

        // ---- PV
        __builtin_amdgcn_s_setprio(1);
        #pragma unroll
        for (int ks = 0; ks < 4; ++ks) {
            const bf8 v0 = *(const bf8*)(kb + (12 + 2 * ks) * 1024);
            const bf8 v1 = *(const bf8*)(kb + (13 + 2 * ks) * 1024);
            oacc0 = __builtin_amdgcn_mfma_f32_32x32x16_bf16(v0, pfv[ks], oacc0, 0, 0, 0);
            oacc1 = __builtin_amdgcn_mfma_f32_32x32x16_bf16(v1, pfv[ks], oacc1, 0, 0, 0);
        }
        __builtin_amdgcn_s_setprio(0);

        if (t + 1 < 32) writeL(cur ^ 1);      // vmcnt wait inserted by compiler
        __syncthreads();
        cur ^= 1;
    }

    // ---- epilogue: partials -> LDS (overlay smem) -> coalesced bf16 dump
    const float ltot = lrun + __shfl_xor(lrun, 32, 64);
    float* osh = (float*)smem;                 // 128 rows x pitch 68 = 34.8 KB
    #pragma unroll
    for (int r = 0; r < 16; ++r) {
        const int d = (r & 3) + 8 * (r >> 2) + 4 * hi;
        osh[(w * 32 + q5) * 68 + d] = oacc0[r];
        osh[(w * 32 + q5) * 68 + 32 + d] = oacc1[r];
    }
    if (hi == 0) l_sh[w * 32 + q5] = ltot;
    __syncthreads();

    __hip_bfloat16* pob = half ? po1 : po0;
    float* lsb = half ? ls1 : ls0;
    const int row = tid >> 1;
    const int dh = (tid & 1) * 32;
    const float* src = &osh[row * 68 + dh];
    __hip_bfloat16* dst = pob + ((size_t)(b * SS + qg * 128 + row) * HID + h * HD + dh);
    #pragma unroll
    for (int j = 0; j < 4; ++j) {
        const f4 x0 = *(const f4*)&src[j * 8];
        const f4 x1 = *(const f4*)&src[j * 8 + 4];
        union { unsigned u[4]; bf8 v; } o;
        o.u[0] = pack2(x0[0], x0[1]); o.u[1] = pack2(x0[2], x0[3]);
        o.u[2] = pack2(x1[0], x1[1]); o.u[3] = pack2(x1[2], x1[3]);
        *(bf8*)&dst[j * 8] = o.v;
    }
    if (tid < 128) lsb[(size_t)(b * SS + qg * 128 + tid) * 4 + h] = l_sh[tid];
}

// ---------------------------------------------------------------------------
// Output projection via MFMA; merges the two KV-half partials during staging.
// ---------------------------------------------------------------------------
__global__ __launch_bounds__(256)
void out_proj_kernel(const __hip_bfloat16* __restrict__ po0,
                     const __hip_bfloat16* __restrict__ po1,
                     const float* __restrict__ ls0,
                     const float* __restrict__ ls1,
                     const __hip_bfloat16* __restrict__ wpk,
                     const float* __restrict__ bo, float* __restrict__ out)
{
    const int bid = blockIdx.x;
    const int stile = bid >> 1, grp = bid & 1;
    const int tid = threadIdx.x;
    const int w = tid >> 6, lane = tid & 63, hi = lane >> 5, l5 = lane & 31;

    __shared__ __hip_bfloat16 xs[32][256];
    {
        const int r0 = tid >> 5, c = tid & 31;
        #pragma unroll
        for (int it = 0; it < 4; ++it) {
            const int row = r0 + it * 8;
            const size_t srow = (size_t)stile * 32 + row;
            const int head = c >> 3;
            const float inv = 1.0f / (ls0[srow * 4 + head] + ls1[srow * 4 + head]);
            union { bf8 v; unsigned u[4]; } a0, a1;
            a0.v = *(const bf8*)&po0[srow * 256 + c * 8];
            a1.v = *(const bf8*)&po1[srow * 256 + c * 8];
            union { unsigned u[4]; bf8 v; } o;
            #pragma unroll
            for (int i = 0; i < 4; ++i) {
                const float lo = __uint_as_float(a0.u[i] << 16)
                               + __uint_as_float(a1.u[i] << 16);
                const float hv = __uint_as_float(a0.u[i] & 0xffff0000u)
                               + __uint_as_float(a1.u[i] & 0xffff0000u);
                o.u[i] = pack2(lo * inv, hv * inv);
            }
            *(bf8*)&xs[row][((c ^ row) & 31) * 8] = o.v;
        }
    }
    __syncthreads();

    const int nt = grp * 4 + w;           // 0..7
    const __hip_bfloat16* wb = wpk + (size_t)((3 * 8 + nt) * 16) * 512 + (size_t)lane * 8;
    bf8 wf[16];
    #pragma unroll
    for (int ks = 0; ks < 16; ++ks) wf[ks] = *(const bf8*)&wb[ks * 512];

    f16v acc;
    #pragma unroll
    for (int r = 0; r < 16; ++r) acc[r] = 0.0f;
    #pragma unroll
    for (int ks = 0; ks < 16; ++ks) {
        const bf8 xf = *(const bf8*)&xs[l5][(((ks * 2 + hi) ^ l5) & 31) * 8];
        acc = __builtin_amdgcn_mfma_f32_32x32x16_bf16(xf, wf[ks], acc, 0, 0, 0);
    }

    const float bn = bo[nt * 32 + l5];
    #pragma unroll
    for (int r = 0; r < 16; ++r) {
        const int sloc = (r & 3) + 8 * (r >> 2) + 4 * hi;
        out[(size_t)(stile * 32 + sloc) * HID + nt * 32 + l5] = acc[r] + bn;
    }
}

extern "C" void kernel_launch(void* const* d_in, const int* in_sizes, int n_in,
                              void* d_out, int out_size, void* d_ws, size_t ws_size,
                              hipStream_t stream)
{
    (void)in_sizes; (void)n_in; (void)out_size; (void)ws_size;
    const float* x        = (const float*)d_in[0];
    const int*   codons   = (const int*)d_in[1];
    const float* syn_bias = (const float*)d_in[2];
    const float* wq = (const float*)d_in[3];
    const float* bq = (const float*)d_in[4];
    const float* wk = (const float*)d_in[5];
    const float* bk = (const float*)d_in[6];
    const float* wv = (const float*)d_in[7];
    const float* bv = (const float*)d_in[8];
    const float* wo = (const float*)d_in[9];
    const float* bo = (const float*)d_in[10];
    float* out = (float*)d_out;

    char* ws = (char*)d_ws;
    int*   gid   = (int*)(ws);                                  // 256 B
    float* betaP = (float*)(ws + 256);                          // 4 B
    __hip_bfloat16* wpk   = (__hip_bfloat16*)(ws + 4096);       // 512 KB
    __hip_bfloat16* qfrag = (__hip_bfloat16*)(ws + (size_t)1048576u);    // 6 MB
    __hip_bfloat16* kfrag = (__hip_bfloat16*)(ws + (size_t)7340032u);    // 6 MB
    __hip_bfloat16* vfrag = (__hip_bfloat16*)(ws + (size_t)13631488u);   // 4 MB
    __hip_bfloat16* po0   = (__hip_bfloat16*)(ws + (size_t)17825792u);   // 4 MB
    __hip_bfloat16* po1   = (__hip_bfloat16*)(ws + (size_t)22020096u);   // 4 MB
    float* ls0            = (float*)(ws + (size_t)26214400u);            // 128 KB
    float* ls1            = (float*)(ws + (size_t)26345472u);            // 128 KB

    setup_kernel<<<1, 64, 0, stream>>>(syn_bias, gid, betaP);
    pack_w_kernel<<<128, 256, 0, stream>>>(wq, wk, wv, wo, wpk);
    qkv_mfma_kernel<<<1536, 256, 0, stream>>>(x, wpk, bq, bk, bv, codons, gid, betaP,
                                              qfrag, kfrag, vfrag);
    attn_kernel<<<512, 256, 0, stream>>>(qfrag, kfrag, vfrag, po0, po1, ls0, ls1);
    out_proj_kernel<<<512, 256, 0, stream>>>(po0, po1, ls0, ls1, wpk, bo, out);
}